// Round 8
// baseline (724.370 us; speedup 1.0000x reference)
//
#include <hip/hip_runtime.h>

#define H 128
#define NSRC 3
#define MSTRIDE 136   // padded f16 row stride for MSG scratch

typedef _Float16 f16;
typedef _Float16 f16x2 __attribute__((ext_vector_type(2)));
typedef _Float16 f16x4 __attribute__((ext_vector_type(4)));
typedef _Float16 f16x8 __attribute__((ext_vector_type(8)));
typedef float f32x4 __attribute__((ext_vector_type(4)));

// ---------------------------------------------------------------------------
// setup: zero cnt, zero AGG, prep W (fp32 [384][128] -> f16 [c][k] transposed,
// pre-swizzled: byte off within src = (c*256 + k*2) ^ ((c&7)<<4))
// ---------------------------------------------------------------------------
__global__ void setup_kernel(const float* __restrict__ W, f16* __restrict__ wbuf,
                             int* __restrict__ cnt, float4* __restrict__ AGG4,
                             int n_nodes, int nagg4) {
    const int i = blockIdx.x * blockDim.x + threadIdx.x;
    const int np = gridDim.x * blockDim.x;
    if (i < NSRC * H * H) {
        int src = i >> 14;
        int k = (i >> 7) & 127;
        int c = i & 127;
        float v = W[((size_t)src * H + k) * H + c];
        unsigned off = ((unsigned)(c * 256 + k * 2)) ^ ((unsigned)((c & 7) << 4));
        wbuf[(size_t)src * (H * H) + (off >> 1)] = (f16)v;
    }
    if (i < n_nodes) cnt[i] = 0;
    for (int j = i; j < nagg4; j += np) AGG4[j] = make_float4(0.f, 0.f, 0.f, 0.f);
}

// ---------------------------------------------------------------------------
__global__ void prep_nf_kernel(const float* __restrict__ nf, f16* __restrict__ nfh, int n) {
    int i = (blockIdx.x * blockDim.x + threadIdx.x) * 4;
    if (i >= n) return;
    float4 v = *(const float4*)(nf + i);
    f16x4 h;
    h[0] = (f16)v.x; h[1] = (f16)v.y; h[2] = (f16)v.z; h[3] = (f16)v.w;
    *(f16x4*)(nfh + i) = h;
}

// ---------------------------------------------------------------------------
// Counting sort by receiver: hist -> scan -> scatter
// ---------------------------------------------------------------------------
__global__ void hist_kernel(const int* __restrict__ recv, int* __restrict__ cnt, int n_edges) {
    int e = blockIdx.x * blockDim.x + threadIdx.x;
    if (e < n_edges) atomicAdd(&cnt[recv[e]], 1);
}

__global__ void scan_kernel(const int* __restrict__ cnt, int* __restrict__ row_ptr,
                            int* __restrict__ cursor, int n) {
    __shared__ int sd[1024];
    const int t = threadIdx.x;
    const int per = (n + 1023) >> 10;
    const int st = t * per;
    const int en = min(st + per, n);
    int s = 0;
    for (int i = st; i < en; ++i) s += cnt[i];
    sd[t] = s;
    __syncthreads();
    for (int off = 1; off < 1024; off <<= 1) {
        int v = 0;
        if (t >= off) v = sd[t - off];
        __syncthreads();
        sd[t] += v;
        __syncthreads();
    }
    int run = sd[t] - s;
    for (int i = st; i < en; ++i) {
        row_ptr[i] = run;
        cursor[i] = run;
        run += cnt[i];
    }
    if (t == 1023) row_ptr[n] = sd[1023];
}

__global__ void scatter_kernel(const int* __restrict__ send, const int* __restrict__ recv,
                               int* __restrict__ cursor, int* __restrict__ perm,
                               int* __restrict__ ssend, int* __restrict__ srecv, int n_edges) {
    int e = blockIdx.x * blockDim.x + threadIdx.x;
    if (e < n_edges) {
        int r = recv[e];
        int pos = atomicAdd(&cursor[r], 1);
        perm[pos] = e;
        ssend[pos] = send[e];
        srecv[pos] = r;
    }
}

// ---------------------------------------------------------------------------
// Node projections (fp32 in, convert on the fly):
//   PS = f16(NF)@W1 (f16 out), PR = f16(NF)@W2 + b (fp32 out)
// ---------------------------------------------------------------------------
__global__ __launch_bounds__(256, 2)
void node_proj_kernel(const float* __restrict__ nf, const float* __restrict__ b,
                      const f16* __restrict__ wbuf, f16* __restrict__ PS,
                      float* __restrict__ PR, int n_nodes) {
    __shared__ __align__(16) f16 Wlds[2 * H * H];  // 64 KB: W1, W2
    const int t = threadIdx.x;
    {
        const int4* g = (const int4*)wbuf;
        int4* d = (int4*)Wlds;
#pragma unroll
        for (int i = 0; i < 16; ++i) d[i * 256 + t] = g[i * 256 + t];
    }
    __syncthreads();

    const int lane = t & 63;
    const int wid = t >> 6;
    const int l15 = lane & 15;
    const int lg = lane >> 4;
    const int r0 = (blockIdx.x * 4 + wid) * 64;
    if (r0 >= n_nodes) return;

#pragma unroll
    for (int src = 0; src < 2; ++src) {
        f32x4 acc[4][8];
#pragma unroll
        for (int rf = 0; rf < 4; ++rf)
#pragma unroll
            for (int cf = 0; cf < 8; ++cf) acc[rf][cf] = (f32x4){0.f, 0.f, 0.f, 0.f};

#pragma unroll
        for (int ks = 0; ks < 4; ++ks) {
            f16x8 a[4];
#pragma unroll
            for (int rf = 0; rf < 4; ++rf) {
                int row = r0 + rf * 16 + l15;
                if (row >= n_nodes) row = n_nodes - 1;
                const float* p = nf + (size_t)row * H + ks * 32 + lg * 8;
                float4 v0 = *(const float4*)p;
                float4 v1 = *(const float4*)(p + 4);
                f16x8 h;
                h[0] = (f16)v0.x; h[1] = (f16)v0.y; h[2] = (f16)v0.z; h[3] = (f16)v0.w;
                h[4] = (f16)v1.x; h[5] = (f16)v1.y; h[6] = (f16)v1.z; h[7] = (f16)v1.w;
                a[rf] = h;
            }
#pragma unroll
            for (int cf = 0; cf < 8; ++cf) {
                const int c = cf * 16 + l15;
                unsigned off = ((unsigned)(src * 32768 + c * 256 + (ks * 32 + lg * 8) * 2))
                               ^ ((unsigned)((c & 7) << 4));
                f16x8 bf = *(const f16x8*)((const char*)Wlds + off);
#pragma unroll
                for (int rf = 0; rf < 4; ++rf)
                    acc[rf][cf] = __builtin_amdgcn_mfma_f32_16x16x32_f16(
                        a[rf], bf, acc[rf][cf], 0, 0, 0);
            }
        }

#pragma unroll
        for (int rf = 0; rf < 4; ++rf) {
#pragma unroll
            for (int q = 0; q < 4; ++q) {
                const int row = r0 + rf * 16 + lg * 4 + q;
                if (row < n_nodes) {
#pragma unroll
                    for (int cf = 0; cf < 8; ++cf) {
                        const int col = cf * 16 + l15;
                        if (src == 0)
                            PS[(size_t)row * H + col] = (f16)acc[rf][cf][q];
                        else
                            PR[(size_t)row * H + col] = acc[rf][cf][q] + b[col];
                    }
                }
            }
        }
    }
}

// ---------------------------------------------------------------------------
// FUSED, barrier-free main loop. Each WAVE owns a 16-sorted-edge window:
//   batched uniform loads of ssend/srecv + batched PS/PR gathers (issued
//   early), EF[perm] gathered direct to registers, MFMA 16x128 (W3 from a
//   once-staged LDS copy), raw messages to a wave-private padded LDS scratch,
//   then pure-register segmented accumulate; one atomicAdd pair per lane per
//   receiver-segment into AGG.
// ---------------------------------------------------------------------------
__global__ __launch_bounds__(256, 3)
void fused_msg_kernel(const float* __restrict__ ef, const int* __restrict__ perm,
                      const int* __restrict__ ssend, const int* __restrict__ srecv,
                      const f16* __restrict__ wbuf, const f16* __restrict__ PS,
                      const float* __restrict__ PR, float* __restrict__ AGG,
                      int n_edges) {
    __shared__ __align__(16) f16 Wlds3[H * H];           // 32 KB: W3 (pre-swizzled)
    __shared__ __align__(16) f16 MSG[4][16 * MSTRIDE];   // 17 KB: per-wave scratch

    const int t = threadIdx.x;
    {
        const int4* g = (const int4*)(wbuf + (size_t)2 * H * H);
        int4* d = (int4*)Wlds3;
#pragma unroll
        for (int i = 0; i < 8; ++i) d[i * 256 + t] = g[i * 256 + t];
    }
    __syncthreads();  // the only barrier

    const int lane = t & 63;
    const int wid = t >> 6;
    const int l15 = lane & 15;
    const int lg = lane >> 4;
    const int c2 = lane * 2;
    f16* msg = MSG[wid];

    const int nwin = (n_edges + 15) >> 4;
    const int nworkers = gridDim.x * 4;

    for (int win = blockIdx.x * 4 + wid; win < nwin; win += nworkers) {
        const int e_base = win * 16;

        // ---- uniform index loads ----
        int sarr[16], rarr[16];
#pragma unroll
        for (int j = 0; j < 16; ++j) {
            int e = min(e_base + j, n_edges - 1);
            sarr[j] = ssend[e];
            rarr[j] = srecv[e];
        }
        // ---- batched PS/PR gathers (latency hides under A-load + MFMA) ----
        f16x2 psv[16];
        float2 prv[16];
#pragma unroll
        for (int j = 0; j < 16; ++j) {
            psv[j] = *(const f16x2*)&PS[(size_t)sarr[j] * H + c2];
            prv[j] = *(const float2*)&PR[(size_t)rarr[j] * H + c2];
        }

        // ---- A direct from EF: row e_base+l15, k = ks*32 + lg*8 ----
        const int erow = min(e_base + l15, n_edges - 1);
        const float* ep = ef + (size_t)perm[erow] * H + lg * 8;
        f16x8 af[4];
#pragma unroll
        for (int ks = 0; ks < 4; ++ks) {
            float4 v0 = *(const float4*)(ep + ks * 32);
            float4 v1 = *(const float4*)(ep + ks * 32 + 4);
            f16x8 h;
            h[0] = (f16)v0.x; h[1] = (f16)v0.y; h[2] = (f16)v0.z; h[3] = (f16)v0.w;
            h[4] = (f16)v1.x; h[5] = (f16)v1.y; h[6] = (f16)v1.z; h[7] = (f16)v1.w;
            af[ks] = h;
        }

        // ---- MFMA: 16 rows x 128 cols, K=128 ----
        f32x4 acc[8];
#pragma unroll
        for (int cf = 0; cf < 8; ++cf) acc[cf] = (f32x4){0.f, 0.f, 0.f, 0.f};
#pragma unroll
        for (int ks = 0; ks < 4; ++ks) {
#pragma unroll
            for (int cf = 0; cf < 8; ++cf) {
                const int c = cf * 16 + l15;
                unsigned off = ((unsigned)(c * 256 + (ks * 32 + lg * 8) * 2))
                               ^ ((unsigned)((c & 7) << 4));
                f16x8 bf = *(const f16x8*)((const char*)Wlds3 + off);
                acc[cf] = __builtin_amdgcn_mfma_f32_16x16x32_f16(af[ks], bf, acc[cf], 0, 0, 0);
            }
        }

        // ---- raw messages -> wave-private MSG (C/D: col=l15, row=lg*4+q) ----
#pragma unroll
        for (int cf = 0; cf < 8; ++cf)
#pragma unroll
            for (int q = 0; q < 4; ++q)
                msg[(lg * 4 + q) * MSTRIDE + cf * 16 + l15] = (f16)acc[cf][q];
        // same-wave LDS ordering: no barrier needed

        // ---- segmented accumulate (all static indices, uniform branches) ----
        float ax = 0.f, ay = 0.f;
#pragma unroll
        for (int j = 0; j < 16; ++j) {
            if (e_base + j < n_edges) {
                f16x2 m = *(const f16x2*)&msg[j * MSTRIDE + c2];
                ax += fmaxf((float)psv[j][0] + prv[j].x + (float)m[0], 0.f);
                ay += fmaxf((float)psv[j][1] + prv[j].y + (float)m[1], 0.f);
                bool flush = (j == 15) || (e_base + j + 1 >= n_edges) ||
                             (rarr[j + 1] != rarr[j]);
                if (flush) {
                    atomicAdd(&AGG[(size_t)rarr[j] * H + c2], ax);
                    atomicAdd(&AGG[(size_t)rarr[j] * H + c2 + 1], ay);
                    ax = 0.f;
                    ay = 0.f;
                }
            }
        }
    }
}

// ---------------------------------------------------------------------------
// LayerNorm(nf + AGG) -> out
// ---------------------------------------------------------------------------
__global__ __launch_bounds__(256, 4)
void ln_agg_kernel(const float* __restrict__ nf, const float* __restrict__ AGG,
                   const float* __restrict__ lnw, const float* __restrict__ lnb,
                   float* __restrict__ out, int n_nodes) {
    const int wv = threadIdx.x >> 6;
    const int lane = threadIdx.x & 63;
    const int row = blockIdx.x * (blockDim.x >> 6) + wv;
    if (row >= n_nodes) return;
    float2 a = ((const float2*)(nf + (size_t)row * H))[lane];
    float2 g = ((const float2*)(AGG + (size_t)row * H))[lane];
    float vx = a.x + g.x, vy = a.y + g.y;

    float s = vx + vy;
#pragma unroll
    for (int m = 32; m; m >>= 1) s += __shfl_xor(s, m, 64);
    float mu = s * (1.f / H);
    float dx = vx - mu, dy = vy - mu;
    float q = dx * dx + dy * dy;
#pragma unroll
    for (int m = 32; m; m >>= 1) q += __shfl_xor(q, m, 64);
    float rs = rsqrtf(q * (1.f / H) + 1e-5f);

    float2 w2 = ((const float2*)lnw)[lane];
    float2 b2 = ((const float2*)lnb)[lane];
    float2 o;
    o.x = dx * rs * w2.x + b2.x;
    o.y = dy * rs * w2.y + b2.y;
    ((float2*)(out + (size_t)row * H))[lane] = o;
}

// ---------------------------------------------------------------------------
// Fallback path (R4): barrier-free fused GEMM with atomics + separate LN
// ---------------------------------------------------------------------------
__global__ __launch_bounds__(512, 2)
void fused_edge_kernel(const f16* __restrict__ nfh, const int* __restrict__ senders,
                       const int* __restrict__ receivers, const float* __restrict__ ef,
                       const float* __restrict__ b, const f16* __restrict__ wbuf,
                       float* __restrict__ out, int n_edges) {
    __shared__ __align__(16) f16 Wlds[NSRC * H * H];  // 96 KB
    const int t = threadIdx.x;
    {
        const int4* g = (const int4*)wbuf;
        int4* d = (int4*)Wlds;
#pragma unroll
        for (int i = 0; i < 12; ++i) d[i * 512 + t] = g[i * 512 + t];
    }
    __syncthreads();

    const int lane = t & 63;
    const int wid = t >> 6;
    const int l15 = lane & 15;
    const int lg = lane >> 4;

    float bias[8];
#pragma unroll
    for (int cf = 0; cf < 8; ++cf) bias[cf] = b[cf * 16 + l15];

    const int ntiles = (n_edges + 63) >> 6;
    const int nworkers = gridDim.x * 8;

    for (int tile = blockIdx.x * 8 + wid; tile < ntiles; tile += nworkers) {
        const int e0 = tile * 64;
        int sid[4], rid[4];
#pragma unroll
        for (int rf = 0; rf < 4; ++rf) {
            int e = e0 + rf * 16 + l15;
            if (e >= n_edges) e = n_edges - 1;
            sid[rf] = senders[e];
            rid[rf] = receivers[e];
        }
        f32x4 acc[4][8];
#pragma unroll
        for (int rf = 0; rf < 4; ++rf)
#pragma unroll
            for (int cf = 0; cf < 8; ++cf) acc[rf][cf] = (f32x4){0.f, 0.f, 0.f, 0.f};

#pragma unroll
        for (int src = 0; src < 2; ++src) {
#pragma unroll
            for (int ks = 0; ks < 4; ++ks) {
                f16x8 a[4];
#pragma unroll
                for (int rf = 0; rf < 4; ++rf) {
                    const int row = (src == 0) ? sid[rf] : rid[rf];
                    a[rf] = *(const f16x8*)(nfh + (size_t)row * H + ks * 32 + lg * 8);
                }
#pragma unroll
                for (int cf = 0; cf < 8; ++cf) {
                    const int c = cf * 16 + l15;
                    unsigned off = ((unsigned)(src * 32768 + c * 256 + (ks * 32 + lg * 8) * 2))
                                   ^ ((unsigned)((c & 7) << 4));
                    f16x8 bf = *(const f16x8*)((const char*)Wlds + off);
#pragma unroll
                    for (int rf = 0; rf < 4; ++rf)
                        acc[rf][cf] = __builtin_amdgcn_mfma_f32_16x16x32_f16(
                            a[rf], bf, acc[rf][cf], 0, 0, 0);
                }
            }
        }
#pragma unroll
        for (int ks = 0; ks < 4; ++ks) {
            f16x8 a[4];
#pragma unroll
            for (int rf = 0; rf < 4; ++rf) {
                int e = e0 + rf * 16 + l15;
                if (e >= n_edges) e = n_edges - 1;
                const float* p = ef + (size_t)e * H + ks * 32 + lg * 8;
                float4 v0 = *(const float4*)p;
                float4 v1 = *(const float4*)(p + 4);
                f16x8 h;
                h[0] = (f16)v0.x; h[1] = (f16)v0.y; h[2] = (f16)v0.z; h[3] = (f16)v0.w;
                h[4] = (f16)v1.x; h[5] = (f16)v1.y; h[6] = (f16)v1.z; h[7] = (f16)v1.w;
                a[rf] = h;
            }
#pragma unroll
            for (int cf = 0; cf < 8; ++cf) {
                const int c = cf * 16 + l15;
                unsigned off = ((unsigned)(2 * 32768 + c * 256 + (ks * 32 + lg * 8) * 2))
                               ^ ((unsigned)((c & 7) << 4));
                f16x8 bf = *(const f16x8*)((const char*)Wlds + off);
#pragma unroll
                for (int rf = 0; rf < 4; ++rf)
                    acc[rf][cf] = __builtin_amdgcn_mfma_f32_16x16x32_f16(
                        a[rf], bf, acc[rf][cf], 0, 0, 0);
            }
        }
#pragma unroll
        for (int rf = 0; rf < 4; ++rf) {
#pragma unroll
            for (int q = 0; q < 4; ++q) {
                const int e = e0 + rf * 16 + lg * 4 + q;
                if (e < n_edges) {
                    const int r = receivers[e];
                    float* dst = out + (size_t)r * H;
#pragma unroll
                    for (int cf = 0; cf < 8; ++cf) {
                        float m = fmaxf(acc[rf][cf][q] + bias[cf], 0.f);
                        atomicAdd(dst + cf * 16 + l15, m);
                    }
                }
            }
        }
    }
}

__global__ __launch_bounds__(256, 4)
void ln_kernel(const float* __restrict__ nf, const float* __restrict__ lnw,
               const float* __restrict__ lnb, float* __restrict__ out, int n_nodes) {
    const int wv = threadIdx.x >> 6;
    const int lane = threadIdx.x & 63;
    const int row = blockIdx.x * (blockDim.x >> 6) + wv;
    if (row >= n_nodes) return;
    float2 a = ((const float2*)(nf + (size_t)row * H))[lane];
    float2 g = ((float2*)(out + (size_t)row * H))[lane];
    float vx = a.x + g.x, vy = a.y + g.y;
    float s = vx + vy;
#pragma unroll
    for (int m = 32; m; m >>= 1) s += __shfl_xor(s, m, 64);
    float mu = s * (1.f / H);
    float dx = vx - mu, dy = vy - mu;
    float q = dx * dx + dy * dy;
#pragma unroll
    for (int m = 32; m; m >>= 1) q += __shfl_xor(q, m, 64);
    float rs = rsqrtf(q * (1.f / H) + 1e-5f);
    float2 w2 = ((const float2*)lnw)[lane];
    float2 b2 = ((const float2*)lnb)[lane];
    float2 o;
    o.x = dx * rs * w2.x + b2.x;
    o.y = dy * rs * w2.y + b2.y;
    ((float2*)(out + (size_t)row * H))[lane] = o;
}

__global__ void naive_edge_kernel(const float* __restrict__ nf, const int* __restrict__ s,
                                  const int* __restrict__ r, const float* __restrict__ ef,
                                  const float* __restrict__ W, const float* __restrict__ b,
                                  float* __restrict__ out, int n_edges) {
    int e = blockIdx.x * 2 + (threadIdx.x >> 7);
    int c = threadIdx.x & 127;
    if (e >= n_edges) return;
    int se = s[e], re = r[e];
    float acc = b[c];
    for (int k = 0; k < H; ++k) {
        acc += nf[(size_t)se * H + k] * W[(size_t)k * H + c];
        acc += nf[(size_t)re * H + k] * W[(size_t)(H + k) * H + c];
        acc += ef[(size_t)e * H + k] * W[(size_t)(2 * H + k) * H + c];
    }
    atomicAdd(&out[(size_t)re * H + c], fmaxf(acc, 0.f));
}

// ---------------------------------------------------------------------------
extern "C" void kernel_launch(void* const* d_in, const int* in_sizes, int n_in,
                              void* d_out, int out_size, void* d_ws, size_t ws_size,
                              hipStream_t stream) {
    const float* nf        = (const float*)d_in[0];
    const int*   senders   = (const int*)d_in[1];
    const int*   receivers = (const int*)d_in[2];
    const float* ef        = (const float*)d_in[3];
    const float* W         = (const float*)d_in[4];
    const float* b         = (const float*)d_in[5];
    const float* lnw       = (const float*)d_in[6];
    const float* lnb       = (const float*)d_in[7];
    float* out = (float*)d_out;

    const int n_nodes = in_sizes[0] / H;  // 50000
    const int n_edges = in_sizes[1];      // 800000
    const int nfelem = n_nodes * H;

    // ws carve-out (256B aligned)
    size_t o = 0;
    auto carve = [&](size_t bytes) { size_t r = o; o += (bytes + 255) & ~(size_t)255; return r; };
    const size_t o_wbuf   = carve((size_t)NSRC * H * H * sizeof(f16));   // 96 KB
    const size_t o_nfh    = carve((size_t)nfelem * sizeof(f16));         // 12.8 MB (fallback only)
    const size_t o_cnt    = carve((size_t)n_nodes * 4);
    const size_t o_rowptr = carve((size_t)(n_nodes + 1) * 4);
    const size_t o_cursor = carve((size_t)n_nodes * 4);
    const size_t o_perm   = carve((size_t)n_edges * 4);
    const size_t o_ssend  = carve((size_t)n_edges * 4);
    const size_t o_srecv  = carve((size_t)n_edges * 4);
    const size_t o_ps     = carve((size_t)nfelem * sizeof(f16));         // 12.8 MB
    const size_t o_pr     = carve((size_t)nfelem * sizeof(float));       // 25.6 MB
    const size_t o_agg    = carve((size_t)nfelem * sizeof(float));       // 25.6 MB
    const size_t need_full = o;

    char* ws = (char*)d_ws;
    f16* wbuf = (f16*)(ws + o_wbuf);
    f16* nfh  = (f16*)(ws + o_nfh);

    if (ws_size >= need_full) {
        int* cnt    = (int*)(ws + o_cnt);
        int* rowptr = (int*)(ws + o_rowptr);
        int* cursor = (int*)(ws + o_cursor);
        int* perm   = (int*)(ws + o_perm);
        int* ssend  = (int*)(ws + o_ssend);
        int* srecv  = (int*)(ws + o_srecv);
        f16* PS     = (f16*)(ws + o_ps);
        float* PR   = (float*)(ws + o_pr);
        float* AGG  = (float*)(ws + o_agg);

        setup_kernel<<<2048, 256, 0, stream>>>(W, wbuf, cnt, (float4*)AGG,
                                               n_nodes, nfelem / 4);
        hist_kernel<<<(n_edges + 255) / 256, 256, 0, stream>>>(receivers, cnt, n_edges);
        scan_kernel<<<1, 1024, 0, stream>>>(cnt, rowptr, cursor, n_nodes);
        scatter_kernel<<<(n_edges + 255) / 256, 256, 0, stream>>>(
            senders, receivers, cursor, perm, ssend, srecv, n_edges);

        const int ntile_n = (n_nodes + 63) / 64;
        node_proj_kernel<<<(ntile_n + 3) / 4, 256, 0, stream>>>(nf, b, wbuf, PS, PR, n_nodes);
        fused_msg_kernel<<<2048, 256, 0, stream>>>(ef, perm, ssend, srecv, wbuf, PS, PR,
                                                   AGG, n_edges);
        ln_agg_kernel<<<(n_nodes + 3) / 4, 256, 0, stream>>>(nf, AGG, lnw, lnb, out, n_nodes);
    } else if (ws_size >= o_cnt) {  // enough for wbuf + nfh: R4 fallback
        hipMemsetAsync(d_out, 0, (size_t)nfelem * sizeof(float), stream);
        setup_kernel<<<64, 256, 0, stream>>>(W, wbuf, (int*)(ws + o_wbuf), (float4*)nullptr, 0, 0);
        prep_nf_kernel<<<(nfelem / 4 + 255) / 256, 256, 0, stream>>>(nf, nfh, nfelem);
        fused_edge_kernel<<<512, 512, 0, stream>>>(nfh, senders, receivers, ef, b,
                                                   wbuf, out, n_edges);
        ln_kernel<<<(n_nodes + 3) / 4, 256, 0, stream>>>(nf, lnw, lnb, out, n_nodes);
    } else {
        hipMemsetAsync(d_out, 0, (size_t)nfelem * sizeof(float), stream);
        naive_edge_kernel<<<(n_edges + 1) / 2, 256, 0, stream>>>(
            nf, senders, receivers, ef, W, b, out, n_edges);
        ln_kernel<<<(n_nodes + 3) / 4, 256, 0, stream>>>(nf, lnw, lnb, out, n_nodes);
    }
}

// Round 9
// 449.117 us; speedup vs baseline: 1.6129x; 1.6129x over previous
//
#include <hip/hip_runtime.h>

#define H 128
#define NSRC 3
#define MSTRIDE 136   // padded f16 row stride for MSG scratch

typedef _Float16 f16;
typedef _Float16 f16x2 __attribute__((ext_vector_type(2)));
typedef _Float16 f16x4 __attribute__((ext_vector_type(4)));
typedef _Float16 f16x8 __attribute__((ext_vector_type(8)));
typedef float f32x4 __attribute__((ext_vector_type(4)));

// ---------------------------------------------------------------------------
// setup: prep W (fp32 [384][128] -> f16 [c][k] transposed, PRE-SWIZZLED:
// byte off within src = (c*256 + k*2) ^ ((c&7)<<4)), zero cnt, zero AGG,
// convert NF fp32 -> f16 (nfh).
// ---------------------------------------------------------------------------
__global__ void setup_kernel(const float* __restrict__ W, f16* __restrict__ wbuf,
                             int* __restrict__ cnt, float4* __restrict__ AGG4,
                             int n_nodes, int nagg4,
                             const float* __restrict__ nf, f16* __restrict__ nfh,
                             int nf4) {
    const int i = blockIdx.x * blockDim.x + threadIdx.x;
    const int np = gridDim.x * blockDim.x;
    if (i < NSRC * H * H) {
        int src = i >> 14;
        int k = (i >> 7) & 127;
        int c = i & 127;
        float v = W[((size_t)src * H + k) * H + c];
        unsigned off = ((unsigned)(c * 256 + k * 2)) ^ ((unsigned)((c & 7) << 4));
        wbuf[(size_t)src * (H * H) + (off >> 1)] = (f16)v;
    }
    if (i < n_nodes) cnt[i] = 0;
    for (int j = i; j < nagg4; j += np) AGG4[j] = make_float4(0.f, 0.f, 0.f, 0.f);
    for (int j = i; j < nf4; j += np) {
        float4 v = ((const float4*)nf)[j];
        f16x4 h;
        h[0] = (f16)v.x; h[1] = (f16)v.y; h[2] = (f16)v.z; h[3] = (f16)v.w;
        ((f16x4*)nfh)[j] = h;
    }
}

// ---------------------------------------------------------------------------
// Counting sort by receiver: hist -> scan -> scatter
// ---------------------------------------------------------------------------
__global__ void hist_kernel(const int* __restrict__ recv, int* __restrict__ cnt, int n_edges) {
    int e = blockIdx.x * blockDim.x + threadIdx.x;
    if (e < n_edges) atomicAdd(&cnt[recv[e]], 1);
}

__global__ void scan_kernel(const int* __restrict__ cnt, int* __restrict__ row_ptr,
                            int* __restrict__ cursor, int n) {
    __shared__ int sd[1024];
    const int t = threadIdx.x;
    const int per = (n + 1023) >> 10;
    const int st = t * per;
    const int en = min(st + per, n);
    int s = 0;
    for (int i = st; i < en; ++i) s += cnt[i];
    sd[t] = s;
    __syncthreads();
    for (int off = 1; off < 1024; off <<= 1) {
        int v = 0;
        if (t >= off) v = sd[t - off];
        __syncthreads();
        sd[t] += v;
        __syncthreads();
    }
    int run = sd[t] - s;
    for (int i = st; i < en; ++i) {
        row_ptr[i] = run;
        cursor[i] = run;
        run += cnt[i];
    }
    if (t == 1023) row_ptr[n] = sd[1023];
}

__global__ void scatter_kernel(const int* __restrict__ send, const int* __restrict__ recv,
                               int* __restrict__ cursor, int* __restrict__ perm,
                               int* __restrict__ ssend, int* __restrict__ srecv, int n_edges) {
    int e = blockIdx.x * blockDim.x + threadIdx.x;
    if (e < n_edges) {
        int r = recv[e];
        int pos = atomicAdd(&cursor[r], 1);
        perm[pos] = e;
        ssend[pos] = send[e];
        srecv[pos] = r;
    }
}

// ---------------------------------------------------------------------------
// FUSED full-K message kernel over sorted edges. Per 64-edge tile:
//  - stage A (3 sources x 64 rows x 128k, f16, XOR-swizzled) into LDS
//      src0 = nfh[ssend[e]] (random gather, L3-resident)
//      src1 = nfh[srecv[e]] (sorted -> ~sequential)
//      src2 = f16(EF[perm[e]]) (512B-granule gather)
//  - MFMA K=384: each wave owns 32 cols, W fragments in registers
//  - MSG transpose via padded LDS
//  - segmented reduce per wave-quarter: +bias, relu, register-accumulate,
//    one atomicAdd pair per lane per receiver segment into AGG.
// No PS/PR/node_proj anywhere. 3 barriers/tile; LDS 66 KB -> 2 blocks/CU.
// ---------------------------------------------------------------------------
__global__ __launch_bounds__(256, 2)
void fused_msg_kernel(const f16* __restrict__ nfh, const float* __restrict__ ef,
                      const int* __restrict__ perm, const int* __restrict__ ssend,
                      const int* __restrict__ srecv, const f16* __restrict__ wbuf,
                      const float* __restrict__ b, float* __restrict__ AGG,
                      int n_edges) {
    __shared__ __align__(16) f16 Alds[NSRC * 64 * H];  // 48 KB
    __shared__ __align__(16) f16 MSG[64 * MSTRIDE];    // 17 KB

    const int t = threadIdx.x;
    const int lane = t & 63;
    const int wid = t >> 6;     // 0..3
    const int l15 = lane & 15;
    const int lg = lane >> 4;
    const int c2 = lane * 2;

    // ---- W fragments in registers: [src][cf][ks], this wave's 32 cols ----
    f16x8 breg[NSRC][2][4];
#pragma unroll
    for (int src = 0; src < NSRC; ++src)
#pragma unroll
        for (int cf = 0; cf < 2; ++cf)
#pragma unroll
            for (int ks = 0; ks < 4; ++ks) {
                const int c = wid * 32 + cf * 16 + l15;
                const int k = ks * 32 + lg * 8;
                unsigned off = ((unsigned)(c * 256 + k * 2)) ^ ((unsigned)((c & 7) << 4));
                breg[src][cf][ks] =
                    *(const f16x8*)((const char*)wbuf + (size_t)src * 32768 + off);
            }

    const float2 bias2 = *(const float2*)&b[c2];

    const int srow = t >> 2;   // staging row 0..63
    const int sq = t & 3;      // staging k-quarter (32 halves)
    const int ntiles = (n_edges + 63) >> 6;

    for (int tile = blockIdx.x; tile < ntiles; tile += gridDim.x) {
        const int e0 = tile * 64;
        __syncthreads();  // prior MFMA (Alds) + prior reduce (MSG) complete

        // ---- stage A: 3 sources ----
        {
            const int e = min(e0 + srow, n_edges - 1);
            const int sidx = ssend[e];
            const int ridx = srecv[e];
            const int pidx = perm[e];
            const int4* ps = (const int4*)(nfh + (size_t)sidx * H + sq * 32);
            const int4* pr = (const int4*)(nfh + (size_t)ridx * H + sq * 32);
            const float4* pe = (const float4*)(ef + (size_t)pidx * H + sq * 32);
#pragma unroll
            for (int i = 0; i < 4; ++i) {
                const int k = sq * 32 + i * 8;
                unsigned off = ((unsigned)(srow * 256 + k * 2))
                               ^ ((unsigned)((srow & 7) << 4));
                *(int4*)((char*)Alds + off) = ps[i];
                *(int4*)((char*)Alds + 16384 + off) = pr[i];
                float4 v0 = pe[i * 2];
                float4 v1 = pe[i * 2 + 1];
                f16x8 h;
                h[0] = (f16)v0.x; h[1] = (f16)v0.y; h[2] = (f16)v0.z; h[3] = (f16)v0.w;
                h[4] = (f16)v1.x; h[5] = (f16)v1.y; h[6] = (f16)v1.z; h[7] = (f16)v1.w;
                *(f16x8*)((char*)Alds + 32768 + off) = h;
            }
        }
        __syncthreads();

        // ---- MFMA: 64 rows x this wave's 32 cols, K=384 ----
        f32x4 acc[4][2];
#pragma unroll
        for (int rf = 0; rf < 4; ++rf) {
            acc[rf][0] = (f32x4){0.f, 0.f, 0.f, 0.f};
            acc[rf][1] = (f32x4){0.f, 0.f, 0.f, 0.f};
        }
#pragma unroll
        for (int src = 0; src < NSRC; ++src)
#pragma unroll
            for (int ks = 0; ks < 4; ++ks) {
                f16x8 af[4];
#pragma unroll
                for (int rf = 0; rf < 4; ++rf) {
                    const int row = rf * 16 + l15;
                    const int k = ks * 32 + lg * 8;
                    unsigned off = ((unsigned)(row * 256 + k * 2))
                                   ^ ((unsigned)((row & 7) << 4));
                    af[rf] = *(const f16x8*)((const char*)Alds + (size_t)src * 16384 + off);
                }
#pragma unroll
                for (int rf = 0; rf < 4; ++rf) {
                    acc[rf][0] = __builtin_amdgcn_mfma_f32_16x16x32_f16(
                        af[rf], breg[src][0][ks], acc[rf][0], 0, 0, 0);
                    acc[rf][1] = __builtin_amdgcn_mfma_f32_16x16x32_f16(
                        af[rf], breg[src][1][ks], acc[rf][1], 0, 0, 0);
                }
            }

        // ---- MSG transpose (C/D: col=l15, row=lg*4+q); disjoint col ranges ----
#pragma unroll
        for (int rf = 0; rf < 4; ++rf)
#pragma unroll
            for (int cf = 0; cf < 2; ++cf)
#pragma unroll
                for (int q = 0; q < 4; ++q)
                    MSG[(rf * 16 + lg * 4 + q) * MSTRIDE + wid * 32 + cf * 16 + l15] =
                        (f16)acc[rf][cf][q];
        __syncthreads();

        // ---- segmented reduce: wave wid owns rows wid*16..+16; no glb loads ----
        int rarr[16];
#pragma unroll
        for (int j = 0; j < 16; ++j)
            rarr[j] = srecv[min(e0 + wid * 16 + j, n_edges - 1)];
        float ax = 0.f, ay = 0.f;
#pragma unroll
        for (int j = 0; j < 16; ++j) {
            const int e = e0 + wid * 16 + j;
            if (e < n_edges) {
                f16x2 m = *(const f16x2*)&MSG[(wid * 16 + j) * MSTRIDE + c2];
                ax += fmaxf((float)m[0] + bias2.x, 0.f);
                ay += fmaxf((float)m[1] + bias2.y, 0.f);
                bool flush = (j == 15) || (e + 1 >= n_edges) || (rarr[j + 1] != rarr[j]);
                if (flush) {
                    atomicAdd(&AGG[(size_t)rarr[j] * H + c2], ax);
                    atomicAdd(&AGG[(size_t)rarr[j] * H + c2 + 1], ay);
                    ax = 0.f;
                    ay = 0.f;
                }
            }
        }
    }
}

// ---------------------------------------------------------------------------
// LayerNorm(nf + AGG) -> out
// ---------------------------------------------------------------------------
__global__ __launch_bounds__(256, 4)
void ln_agg_kernel(const float* __restrict__ nf, const float* __restrict__ AGG,
                   const float* __restrict__ lnw, const float* __restrict__ lnb,
                   float* __restrict__ out, int n_nodes) {
    const int wv = threadIdx.x >> 6;
    const int lane = threadIdx.x & 63;
    const int row = blockIdx.x * (blockDim.x >> 6) + wv;
    if (row >= n_nodes) return;
    float2 a = ((const float2*)(nf + (size_t)row * H))[lane];
    float2 g = ((const float2*)(AGG + (size_t)row * H))[lane];
    float vx = a.x + g.x, vy = a.y + g.y;

    float s = vx + vy;
#pragma unroll
    for (int m = 32; m; m >>= 1) s += __shfl_xor(s, m, 64);
    float mu = s * (1.f / H);
    float dx = vx - mu, dy = vy - mu;
    float q = dx * dx + dy * dy;
#pragma unroll
    for (int m = 32; m; m >>= 1) q += __shfl_xor(q, m, 64);
    float rs = rsqrtf(q * (1.f / H) + 1e-5f);

    float2 w2 = ((const float2*)lnw)[lane];
    float2 b2 = ((const float2*)lnb)[lane];
    float2 o;
    o.x = dx * rs * w2.x + b2.x;
    o.y = dy * rs * w2.y + b2.y;
    ((float2*)(out + (size_t)row * H))[lane] = o;
}

// ---------------------------------------------------------------------------
// Fallback path (R4): barrier-free fused GEMM with atomics + separate LN
// ---------------------------------------------------------------------------
__global__ __launch_bounds__(512, 2)
void fused_edge_kernel(const f16* __restrict__ nfh, const int* __restrict__ senders,
                       const int* __restrict__ receivers, const float* __restrict__ ef,
                       const float* __restrict__ b, const f16* __restrict__ wbuf,
                       float* __restrict__ out, int n_edges) {
    __shared__ __align__(16) f16 Wlds[NSRC * H * H];  // 96 KB
    const int t = threadIdx.x;
    {
        const int4* g = (const int4*)wbuf;
        int4* d = (int4*)Wlds;
#pragma unroll
        for (int i = 0; i < 12; ++i) d[i * 512 + t] = g[i * 512 + t];
    }
    __syncthreads();

    const int lane = t & 63;
    const int wid = t >> 6;
    const int l15 = lane & 15;
    const int lg = lane >> 4;

    float bias[8];
#pragma unroll
    for (int cf = 0; cf < 8; ++cf) bias[cf] = b[cf * 16 + l15];

    const int ntiles = (n_edges + 63) >> 6;
    const int nworkers = gridDim.x * 8;

    for (int tile = blockIdx.x * 8 + wid; tile < ntiles; tile += nworkers) {
        const int e0 = tile * 64;
        int sid[4], rid[4];
#pragma unroll
        for (int rf = 0; rf < 4; ++rf) {
            int e = e0 + rf * 16 + l15;
            if (e >= n_edges) e = n_edges - 1;
            sid[rf] = senders[e];
            rid[rf] = receivers[e];
        }
        f32x4 acc[4][8];
#pragma unroll
        for (int rf = 0; rf < 4; ++rf)
#pragma unroll
            for (int cf = 0; cf < 8; ++cf) acc[rf][cf] = (f32x4){0.f, 0.f, 0.f, 0.f};

#pragma unroll
        for (int src = 0; src < 2; ++src) {
#pragma unroll
            for (int ks = 0; ks < 4; ++ks) {
                f16x8 a[4];
#pragma unroll
                for (int rf = 0; rf < 4; ++rf) {
                    const int row = (src == 0) ? sid[rf] : rid[rf];
                    a[rf] = *(const f16x8*)(nfh + (size_t)row * H + ks * 32 + lg * 8);
                }
#pragma unroll
                for (int cf = 0; cf < 8; ++cf) {
                    const int c = cf * 16 + l15;
                    unsigned off = ((unsigned)(src * 32768 + c * 256 + (ks * 32 + lg * 8) * 2))
                                   ^ ((unsigned)((c & 7) << 4));
                    f16x8 bf = *(const f16x8*)((const char*)Wlds + off);
#pragma unroll
                    for (int rf = 0; rf < 4; ++rf)
                        acc[rf][cf] = __builtin_amdgcn_mfma_f32_16x16x32_f16(
                            a[rf], bf, acc[rf][cf], 0, 0, 0);
                }
            }
        }
#pragma unroll
        for (int ks = 0; ks < 4; ++ks) {
            f16x8 a[4];
#pragma unroll
            for (int rf = 0; rf < 4; ++rf) {
                int e = e0 + rf * 16 + l15;
                if (e >= n_edges) e = n_edges - 1;
                const float* p = ef + (size_t)e * H + ks * 32 + lg * 8;
                float4 v0 = *(const float4*)p;
                float4 v1 = *(const float4*)(p + 4);
                f16x8 h;
                h[0] = (f16)v0.x; h[1] = (f16)v0.y; h[2] = (f16)v0.z; h[3] = (f16)v0.w;
                h[4] = (f16)v1.x; h[5] = (f16)v1.y; h[6] = (f16)v1.z; h[7] = (f16)v1.w;
                a[rf] = h;
            }
#pragma unroll
            for (int cf = 0; cf < 8; ++cf) {
                const int c = cf * 16 + l15;
                unsigned off = ((unsigned)(2 * 32768 + c * 256 + (ks * 32 + lg * 8) * 2))
                               ^ ((unsigned)((c & 7) << 4));
                f16x8 bf = *(const f16x8*)((const char*)Wlds + off);
#pragma unroll
                for (int rf = 0; rf < 4; ++rf)
                    acc[rf][cf] = __builtin_amdgcn_mfma_f32_16x16x32_f16(
                        a[rf], bf, acc[rf][cf], 0, 0, 0);
            }
        }
#pragma unroll
        for (int rf = 0; rf < 4; ++rf) {
#pragma unroll
            for (int q = 0; q < 4; ++q) {
                const int e = e0 + rf * 16 + lg * 4 + q;
                if (e < n_edges) {
                    const int r = receivers[e];
                    float* dst = out + (size_t)r * H;
#pragma unroll
                    for (int cf = 0; cf < 8; ++cf) {
                        float m = fmaxf(acc[rf][cf][q] + bias[cf], 0.f);
                        atomicAdd(dst + cf * 16 + l15, m);
                    }
                }
            }
        }
    }
}

__global__ __launch_bounds__(256, 4)
void ln_kernel(const float* __restrict__ nf, const float* __restrict__ lnw,
               const float* __restrict__ lnb, float* __restrict__ out, int n_nodes) {
    const int wv = threadIdx.x >> 6;
    const int lane = threadIdx.x & 63;
    const int row = blockIdx.x * (blockDim.x >> 6) + wv;
    if (row >= n_nodes) return;
    float2 a = ((const float2*)(nf + (size_t)row * H))[lane];
    float2 g = ((float2*)(out + (size_t)row * H))[lane];
    float vx = a.x + g.x, vy = a.y + g.y;
    float s = vx + vy;
#pragma unroll
    for (int m = 32; m; m >>= 1) s += __shfl_xor(s, m, 64);
    float mu = s * (1.f / H);
    float dx = vx - mu, dy = vy - mu;
    float q = dx * dx + dy * dy;
#pragma unroll
    for (int m = 32; m; m >>= 1) q += __shfl_xor(q, m, 64);
    float rs = rsqrtf(q * (1.f / H) + 1e-5f);
    float2 w2 = ((const float2*)lnw)[lane];
    float2 b2 = ((const float2*)lnb)[lane];
    float2 o;
    o.x = dx * rs * w2.x + b2.x;
    o.y = dy * rs * w2.y + b2.y;
    ((float2*)(out + (size_t)row * H))[lane] = o;
}

__global__ void naive_edge_kernel(const float* __restrict__ nf, const int* __restrict__ s,
                                  const int* __restrict__ r, const float* __restrict__ ef,
                                  const float* __restrict__ W, const float* __restrict__ b,
                                  float* __restrict__ out, int n_edges) {
    int e = blockIdx.x * 2 + (threadIdx.x >> 7);
    int c = threadIdx.x & 127;
    if (e >= n_edges) return;
    int se = s[e], re = r[e];
    float acc = b[c];
    for (int k = 0; k < H; ++k) {
        acc += nf[(size_t)se * H + k] * W[(size_t)k * H + c];
        acc += nf[(size_t)re * H + k] * W[(size_t)(H + k) * H + c];
        acc += ef[(size_t)e * H + k] * W[(size_t)(2 * H + k) * H + c];
    }
    atomicAdd(&out[(size_t)re * H + c], fmaxf(acc, 0.f));
}

// ---------------------------------------------------------------------------
extern "C" void kernel_launch(void* const* d_in, const int* in_sizes, int n_in,
                              void* d_out, int out_size, void* d_ws, size_t ws_size,
                              hipStream_t stream) {
    const float* nf        = (const float*)d_in[0];
    const int*   senders   = (const int*)d_in[1];
    const int*   receivers = (const int*)d_in[2];
    const float* ef        = (const float*)d_in[3];
    const float* W         = (const float*)d_in[4];
    const float* b         = (const float*)d_in[5];
    const float* lnw       = (const float*)d_in[6];
    const float* lnb       = (const float*)d_in[7];
    float* out = (float*)d_out;

    const int n_nodes = in_sizes[0] / H;  // 50000
    const int n_edges = in_sizes[1];      // 800000
    const int nfelem = n_nodes * H;

    // ws carve-out (256B aligned)
    size_t o = 0;
    auto carve = [&](size_t bytes) { size_t r = o; o += (bytes + 255) & ~(size_t)255; return r; };
    const size_t o_wbuf   = carve((size_t)NSRC * H * H * sizeof(f16));   // 96 KB
    const size_t o_nfh    = carve((size_t)nfelem * sizeof(f16));         // 12.8 MB
    const size_t o_cnt    = carve((size_t)n_nodes * 4);
    const size_t o_rowptr = carve((size_t)(n_nodes + 1) * 4);
    const size_t o_cursor = carve((size_t)n_nodes * 4);
    const size_t o_perm   = carve((size_t)n_edges * 4);
    const size_t o_ssend  = carve((size_t)n_edges * 4);
    const size_t o_srecv  = carve((size_t)n_edges * 4);
    const size_t o_agg    = carve((size_t)nfelem * sizeof(float));       // 25.6 MB
    const size_t need_full = o;

    char* ws = (char*)d_ws;
    f16* wbuf = (f16*)(ws + o_wbuf);
    f16* nfh  = (f16*)(ws + o_nfh);

    if (ws_size >= need_full) {
        int* cnt    = (int*)(ws + o_cnt);
        int* rowptr = (int*)(ws + o_rowptr);
        int* cursor = (int*)(ws + o_cursor);
        int* perm   = (int*)(ws + o_perm);
        int* ssend  = (int*)(ws + o_ssend);
        int* srecv  = (int*)(ws + o_srecv);
        float* AGG  = (float*)(ws + o_agg);

        setup_kernel<<<2048, 256, 0, stream>>>(W, wbuf, cnt, (float4*)AGG,
                                               n_nodes, nfelem / 4, nf, nfh, nfelem / 4);
        hist_kernel<<<(n_edges + 255) / 256, 256, 0, stream>>>(receivers, cnt, n_edges);
        scan_kernel<<<1, 1024, 0, stream>>>(cnt, rowptr, cursor, n_nodes);
        scatter_kernel<<<(n_edges + 255) / 256, 256, 0, stream>>>(
            senders, receivers, cursor, perm, ssend, srecv, n_edges);

        fused_msg_kernel<<<1024, 256, 0, stream>>>(nfh, ef, perm, ssend, srecv,
                                                   wbuf, b, AGG, n_edges);
        ln_agg_kernel<<<(n_nodes + 3) / 4, 256, 0, stream>>>(nf, AGG, lnw, lnb, out, n_nodes);
    } else if (ws_size >= o_cnt) {  // enough for wbuf + nfh: R4 fallback
        hipMemsetAsync(d_out, 0, (size_t)nfelem * sizeof(float), stream);
        setup_kernel<<<2048, 256, 0, stream>>>(W, wbuf, (int*)(ws + o_wbuf), nullptr,
                                               0, 0, nf, nfh, nfelem / 4);
        fused_edge_kernel<<<512, 512, 0, stream>>>(nfh, senders, receivers, ef, b,
                                                   wbuf, out, n_edges);
        ln_kernel<<<(n_nodes + 3) / 4, 256, 0, stream>>>(nf, lnw, lnb, out, n_nodes);
    } else {
        hipMemsetAsync(d_out, 0, (size_t)nfelem * sizeof(float), stream);
        naive_edge_kernel<<<(n_edges + 1) / 2, 256, 0, stream>>>(
            nf, senders, receivers, ef, W, b, out, n_edges);
        ln_kernel<<<(n_nodes + 3) / 4, 256, 0, stream>>>(nf, lnw, lnb, out, n_nodes);
    }
}

// Round 10
// 391.576 us; speedup vs baseline: 1.8499x; 1.1469x over previous
//
#include <hip/hip_runtime.h>

#define H 128
#define NSRC 3
#define MSTRIDE 132   // padded f16 row stride: 264 B = 66 dwords = 2 mod 32 -> conflict-free

typedef _Float16 f16;
typedef _Float16 f16x2 __attribute__((ext_vector_type(2)));
typedef _Float16 f16x4 __attribute__((ext_vector_type(4)));
typedef _Float16 f16x8 __attribute__((ext_vector_type(8)));
typedef float f32x4 __attribute__((ext_vector_type(4)));

// ---------------------------------------------------------------------------
// setup: prep W (fp32 [384][128] -> f16 [c][k] transposed, PRE-SWIZZLED:
// byte off within src = (c*256 + k*2) ^ ((c&7)<<4)), zero cnt, zero AGG,
// convert NF fp32 -> f16 (nfh).
// ---------------------------------------------------------------------------
__global__ void setup_kernel(const float* __restrict__ W, f16* __restrict__ wbuf,
                             int* __restrict__ cnt, float4* __restrict__ AGG4,
                             int n_nodes, int nagg4,
                             const float* __restrict__ nf, f16* __restrict__ nfh,
                             int nf4) {
    const int i = blockIdx.x * blockDim.x + threadIdx.x;
    const int np = gridDim.x * blockDim.x;
    if (i < NSRC * H * H) {
        int src = i >> 14;
        int k = (i >> 7) & 127;
        int c = i & 127;
        float v = W[((size_t)src * H + k) * H + c];
        unsigned off = ((unsigned)(c * 256 + k * 2)) ^ ((unsigned)((c & 7) << 4));
        wbuf[(size_t)src * (H * H) + (off >> 1)] = (f16)v;
    }
    if (i < n_nodes) cnt[i] = 0;
    for (int j = i; j < nagg4; j += np) AGG4[j] = make_float4(0.f, 0.f, 0.f, 0.f);
    for (int j = i; j < nf4; j += np) {
        float4 v = ((const float4*)nf)[j];
        f16x4 h;
        h[0] = (f16)v.x; h[1] = (f16)v.y; h[2] = (f16)v.z; h[3] = (f16)v.w;
        ((f16x4*)nfh)[j] = h;
    }
}

// ---------------------------------------------------------------------------
// Counting sort by receiver: hist -> scan -> scatter
// ---------------------------------------------------------------------------
__global__ void hist_kernel(const int* __restrict__ recv, int* __restrict__ cnt, int n_edges) {
    int e = blockIdx.x * blockDim.x + threadIdx.x;
    if (e < n_edges) atomicAdd(&cnt[recv[e]], 1);
}

__global__ void scan_kernel(const int* __restrict__ cnt, int* __restrict__ row_ptr,
                            int* __restrict__ cursor, int n) {
    __shared__ int sd[1024];
    const int t = threadIdx.x;
    const int per = (n + 1023) >> 10;
    const int st = t * per;
    const int en = min(st + per, n);
    int s = 0;
    for (int i = st; i < en; ++i) s += cnt[i];
    sd[t] = s;
    __syncthreads();
    for (int off = 1; off < 1024; off <<= 1) {
        int v = 0;
        if (t >= off) v = sd[t - off];
        __syncthreads();
        sd[t] += v;
        __syncthreads();
    }
    int run = sd[t] - s;
    for (int i = st; i < en; ++i) {
        row_ptr[i] = run;
        cursor[i] = run;
        run += cnt[i];
    }
    if (t == 1023) row_ptr[n] = sd[1023];
}

__global__ void scatter_kernel(const int* __restrict__ send, const int* __restrict__ recv,
                               int* __restrict__ cursor, int* __restrict__ perm,
                               int* __restrict__ ssend, int* __restrict__ srecv, int n_edges) {
    int e = blockIdx.x * blockDim.x + threadIdx.x;
    if (e < n_edges) {
        int r = recv[e];
        int pos = atomicAdd(&cursor[r], 1);
        perm[pos] = e;
        ssend[pos] = send[e];
        srecv[pos] = r;
    }
}

// ---------------------------------------------------------------------------
// FUSED full-K message kernel over sorted edges, SOFTWARE-PIPELINED.
// Per 64-edge tile: stage A (3 sources, f16, XOR-swizzled LDS), MFMA K=384
// (W in registers), MSG transpose via padded LDS, segmented reduce with
// one atomicAdd pair per lane per receiver segment.
// Pipeline: EF data + sender data + indices for tile t+1 prefetched into
// REGISTERS (static names only) during tile t's compute; receiver rows
// (sorted -> L2-friendly) loaded at stage time.
// ---------------------------------------------------------------------------
__global__ __launch_bounds__(256, 2)
void fused_msg_kernel(const f16* __restrict__ nfh, const float* __restrict__ ef,
                      const int* __restrict__ perm, const int* __restrict__ ssend,
                      const int* __restrict__ srecv, const f16* __restrict__ wbuf,
                      const float* __restrict__ b, float* __restrict__ AGG,
                      int n_edges) {
    __shared__ __align__(16) f16 Alds[NSRC * 64 * H];  // 48 KB
    __shared__ __align__(16) f16 MSG[64 * MSTRIDE];    // 16.9 KB
    __shared__ int SR[64];

    const int t = threadIdx.x;
    const int lane = t & 63;
    const int wid = t >> 6;     // 0..3
    const int l15 = lane & 15;
    const int lg = lane >> 4;
    const int c2 = lane * 2;

    // ---- W fragments in registers: [src][cf][ks], this wave's 32 cols ----
    f16x8 breg[NSRC][2][4];
#pragma unroll
    for (int src = 0; src < NSRC; ++src)
#pragma unroll
        for (int cf = 0; cf < 2; ++cf)
#pragma unroll
            for (int ks = 0; ks < 4; ++ks) {
                const int c = wid * 32 + cf * 16 + l15;
                const int k = ks * 32 + lg * 8;
                unsigned off = ((unsigned)(c * 256 + k * 2)) ^ ((unsigned)((c & 7) << 4));
                breg[src][cf][ks] =
                    *(const f16x8*)((const char*)wbuf + (size_t)src * 32768 + off);
            }

    const float2 bias2 = *(const float2*)&b[c2];
    const int srow = t >> 2;   // staging row 0..63
    const int sq = t & 3;      // staging k-quarter
    const int ntiles = (n_edges + 63) >> 6;
    const int stride = gridDim.x;

    // ---- pipeline registers (all static names) ----
    int cs = 0, cr = 0, cp = 0;                 // indices, current tile
    int ns = 0, nr = 0, np = 0;                 // indices, next tile
    int4 s0, s1, s2, s3;                        // sender nfh row quarter (64 B)
    float4 e0, e1, e2, e3, e4, e5, e6, e7;      // EF row quarter (128 B)

    int tile = blockIdx.x;
    if (tile < ntiles) {
        const int e = min(tile * 64 + srow, n_edges - 1);
        cs = ssend[e]; cr = srecv[e]; cp = perm[e];
        const int4* ps = (const int4*)(nfh + (size_t)cs * H + sq * 32);
        s0 = ps[0]; s1 = ps[1]; s2 = ps[2]; s3 = ps[3];
        const float4* pe = (const float4*)(ef + (size_t)cp * H + sq * 32);
        e0 = pe[0]; e1 = pe[1]; e2 = pe[2]; e3 = pe[3];
        e4 = pe[4]; e5 = pe[5]; e6 = pe[6]; e7 = pe[7];
    }
    if (tile + stride < ntiles) {
        const int e = min((tile + stride) * 64 + srow, n_edges - 1);
        ns = ssend[e]; nr = srecv[e]; np = perm[e];
    }

    for (; tile < ntiles; tile += stride) {
        const int e0base = tile * 64;
        __syncthreads();  // Alds free (prev MFMA done), MSG free (prev reduce done)

        // ---- stage: write prefetched sender + EF data ----
        {
            const unsigned ob = ((unsigned)(srow * 256 + sq * 64))
                                ^ ((unsigned)((srow & 7) << 4));
            // sender rows (prefetched)
            *(int4*)((char*)Alds + (ob ^ 0));        // no-op pattern avoided; write directly:
        }
        {
            unsigned off0 = ((unsigned)(srow * 256 + (sq * 32 + 0) * 2)) ^ ((unsigned)((srow & 7) << 4));
            unsigned off1 = ((unsigned)(srow * 256 + (sq * 32 + 8) * 2)) ^ ((unsigned)((srow & 7) << 4));
            unsigned off2 = ((unsigned)(srow * 256 + (sq * 32 + 16) * 2)) ^ ((unsigned)((srow & 7) << 4));
            unsigned off3 = ((unsigned)(srow * 256 + (sq * 32 + 24) * 2)) ^ ((unsigned)((srow & 7) << 4));
            *(int4*)((char*)Alds + off0) = s0;
            *(int4*)((char*)Alds + off1) = s1;
            *(int4*)((char*)Alds + off2) = s2;
            *(int4*)((char*)Alds + off3) = s3;
            // EF rows (prefetched fp32 -> f16)
            f16x8 h0, h1, h2, h3;
#pragma unroll
            for (int j = 0; j < 4; ++j) { h0[j] = (f16)(&e0.x)[j]; h0[j + 4] = (f16)(&e1.x)[j]; }
#pragma unroll
            for (int j = 0; j < 4; ++j) { h1[j] = (f16)(&e2.x)[j]; h1[j + 4] = (f16)(&e3.x)[j]; }
#pragma unroll
            for (int j = 0; j < 4; ++j) { h2[j] = (f16)(&e4.x)[j]; h2[j + 4] = (f16)(&e5.x)[j]; }
#pragma unroll
            for (int j = 0; j < 4; ++j) { h3[j] = (f16)(&e6.x)[j]; h3[j + 4] = (f16)(&e7.x)[j]; }
            *(f16x8*)((char*)Alds + 32768 + off0) = h0;
            *(f16x8*)((char*)Alds + 32768 + off1) = h1;
            *(f16x8*)((char*)Alds + 32768 + off2) = h2;
            *(f16x8*)((char*)Alds + 32768 + off3) = h3;
            // receiver rows (unpipelined; sorted -> L2-friendly)
            const int4* pr = (const int4*)(nfh + (size_t)cr * H + sq * 32);
            int4 r0 = pr[0], r1 = pr[1], r2 = pr[2], r3 = pr[3];
            *(int4*)((char*)Alds + 16384 + off0) = r0;
            *(int4*)((char*)Alds + 16384 + off1) = r1;
            *(int4*)((char*)Alds + 16384 + off2) = r2;
            *(int4*)((char*)Alds + 16384 + off3) = r3;
            if (sq == 0) SR[srow] = cr;
        }

        // ---- issue prefetches for next tiles (fly under MFMA + reduce) ----
        int t2s = 0, t2r = 0, t2p = 0;
        if (tile + 2 * stride < ntiles) {
            const int e = min((tile + 2 * stride) * 64 + srow, n_edges - 1);
            t2s = ssend[e]; t2r = srecv[e]; t2p = perm[e];
        }
        if (tile + stride < ntiles) {
            const int4* ps = (const int4*)(nfh + (size_t)ns * H + sq * 32);
            s0 = ps[0]; s1 = ps[1]; s2 = ps[2]; s3 = ps[3];
            const float4* pe = (const float4*)(ef + (size_t)np * H + sq * 32);
            e0 = pe[0]; e1 = pe[1]; e2 = pe[2]; e3 = pe[3];
            e4 = pe[4]; e5 = pe[5]; e6 = pe[6]; e7 = pe[7];
        }
        __syncthreads();  // Alds ready

        // ---- MFMA: 64 rows x this wave's 32 cols, K=384 ----
        f32x4 acc[4][2];
#pragma unroll
        for (int rf = 0; rf < 4; ++rf) {
            acc[rf][0] = (f32x4){0.f, 0.f, 0.f, 0.f};
            acc[rf][1] = (f32x4){0.f, 0.f, 0.f, 0.f};
        }
#pragma unroll
        for (int src = 0; src < NSRC; ++src)
#pragma unroll
            for (int ks = 0; ks < 4; ++ks) {
                f16x8 af[4];
#pragma unroll
                for (int rf = 0; rf < 4; ++rf) {
                    const int row = rf * 16 + l15;
                    const int k = ks * 32 + lg * 8;
                    unsigned off = ((unsigned)(row * 256 + k * 2))
                                   ^ ((unsigned)((row & 7) << 4));
                    af[rf] = *(const f16x8*)((const char*)Alds + (size_t)src * 16384 + off);
                }
#pragma unroll
                for (int rf = 0; rf < 4; ++rf) {
                    acc[rf][0] = __builtin_amdgcn_mfma_f32_16x16x32_f16(
                        af[rf], breg[src][0][ks], acc[rf][0], 0, 0, 0);
                    acc[rf][1] = __builtin_amdgcn_mfma_f32_16x16x32_f16(
                        af[rf], breg[src][1][ks], acc[rf][1], 0, 0, 0);
                }
            }

        // ---- MSG transpose (C/D: col=l15, row=lg*4+q) ----
#pragma unroll
        for (int rf = 0; rf < 4; ++rf)
#pragma unroll
            for (int cf = 0; cf < 2; ++cf)
#pragma unroll
                for (int q = 0; q < 4; ++q)
                    MSG[(rf * 16 + lg * 4 + q) * MSTRIDE + wid * 32 + cf * 16 + l15] =
                        (f16)acc[rf][cf][q];
        __syncthreads();

        // ---- segmented reduce: wave wid owns rows wid*16..+16 ----
        int rarr[16];
#pragma unroll
        for (int j = 0; j < 16; ++j) rarr[j] = SR[wid * 16 + j];
        float ax = 0.f, ay = 0.f;
#pragma unroll
        for (int j = 0; j < 16; ++j) {
            const int e = e0base + wid * 16 + j;
            if (e < n_edges) {
                f16x2 m = *(const f16x2*)&MSG[(wid * 16 + j) * MSTRIDE + c2];
                ax += fmaxf((float)m[0] + bias2.x, 0.f);
                ay += fmaxf((float)m[1] + bias2.y, 0.f);
                bool flush = (j == 15) || (e + 1 >= n_edges) || (rarr[j + 1] != rarr[j]);
                if (flush) {
                    atomicAdd(&AGG[(size_t)rarr[j] * H + c2], ax);
                    atomicAdd(&AGG[(size_t)rarr[j] * H + c2 + 1], ay);
                    ax = 0.f;
                    ay = 0.f;
                }
            }
        }

        // ---- rotate pipeline registers ----
        cs = ns; cr = nr; cp = np;
        ns = t2s; nr = t2r; np = t2p;
    }
}

// ---------------------------------------------------------------------------
// LayerNorm(nf + AGG) -> out
// ---------------------------------------------------------------------------
__global__ __launch_bounds__(256, 4)
void ln_agg_kernel(const float* __restrict__ nf, const float* __restrict__ AGG,
                   const float* __restrict__ lnw, const float* __restrict__ lnb,
                   float* __restrict__ out, int n_nodes) {
    const int wv = threadIdx.x >> 6;
    const int lane = threadIdx.x & 63;
    const int row = blockIdx.x * (blockDim.x >> 6) + wv;
    if (row >= n_nodes) return;
    float2 a = ((const float2*)(nf + (size_t)row * H))[lane];
    float2 g = ((const float2*)(AGG + (size_t)row * H))[lane];
    float vx = a.x + g.x, vy = a.y + g.y;

    float s = vx + vy;
#pragma unroll
    for (int m = 32; m; m >>= 1) s += __shfl_xor(s, m, 64);
    float mu = s * (1.f / H);
    float dx = vx - mu, dy = vy - mu;
    float q = dx * dx + dy * dy;
#pragma unroll
    for (int m = 32; m; m >>= 1) q += __shfl_xor(q, m, 64);
    float rs = rsqrtf(q * (1.f / H) + 1e-5f);

    float2 w2 = ((const float2*)lnw)[lane];
    float2 b2 = ((const float2*)lnb)[lane];
    float2 o;
    o.x = dx * rs * w2.x + b2.x;
    o.y = dy * rs * w2.y + b2.y;
    ((float2*)(out + (size_t)row * H))[lane] = o;
}

// ---------------------------------------------------------------------------
// Fallback path (R4): barrier-free fused GEMM with atomics + separate LN
// ---------------------------------------------------------------------------
__global__ __launch_bounds__(512, 2)
void fused_edge_kernel(const f16* __restrict__ nfh, const int* __restrict__ senders,
                       const int* __restrict__ receivers, const float* __restrict__ ef,
                       const float* __restrict__ b, const f16* __restrict__ wbuf,
                       float* __restrict__ out, int n_edges) {
    __shared__ __align__(16) f16 Wlds[NSRC * H * H];  // 96 KB
    const int t = threadIdx.x;
    {
        const int4* g = (const int4*)wbuf;
        int4* d = (int4*)Wlds;
#pragma unroll
        for (int i = 0; i < 12; ++i) d[i * 512 + t] = g[i * 512 + t];
    }
    __syncthreads();

    const int lane = t & 63;
    const int wid = t >> 6;
    const int l15 = lane & 15;
    const int lg = lane >> 4;

    float bias[8];
#pragma unroll
    for (int cf = 0; cf < 8; ++cf) bias[cf] = b[cf * 16 + l15];

    const int ntiles = (n_edges + 63) >> 6;
    const int nworkers = gridDim.x * 8;

    for (int tile = blockIdx.x * 8 + wid; tile < ntiles; tile += nworkers) {
        const int e0 = tile * 64;
        int sid[4], rid[4];
#pragma unroll
        for (int rf = 0; rf < 4; ++rf) {
            int e = e0 + rf * 16 + l15;
            if (e >= n_edges) e = n_edges - 1;
            sid[rf] = senders[e];
            rid[rf] = receivers[e];
        }
        f32x4 acc[4][8];
#pragma unroll
        for (int rf = 0; rf < 4; ++rf)
#pragma unroll
            for (int cf = 0; cf < 8; ++cf) acc[rf][cf] = (f32x4){0.f, 0.f, 0.f, 0.f};

#pragma unroll
        for (int src = 0; src < 2; ++src) {
#pragma unroll
            for (int ks = 0; ks < 4; ++ks) {
                f16x8 a[4];
#pragma unroll
                for (int rf = 0; rf < 4; ++rf) {
                    const int row = (src == 0) ? sid[rf] : rid[rf];
                    a[rf] = *(const f16x8*)(nfh + (size_t)row * H + ks * 32 + lg * 8);
                }
#pragma unroll
                for (int cf = 0; cf < 8; ++cf) {
                    const int c = cf * 16 + l15;
                    unsigned off = ((unsigned)(src * 32768 + c * 256 + (ks * 32 + lg * 8) * 2))
                                   ^ ((unsigned)((c & 7) << 4));
                    f16x8 bf = *(const f16x8*)((const char*)Wlds + off);
#pragma unroll
                    for (int rf = 0; rf < 4; ++rf)
                        acc[rf][cf] = __builtin_amdgcn_mfma_f32_16x16x32_f16(
                            a[rf], bf, acc[rf][cf], 0, 0, 0);
                }
            }
        }
#pragma unroll
        for (int ks = 0; ks < 4; ++ks) {
            f16x8 a[4];
#pragma unroll
            for (int rf = 0; rf < 4; ++rf) {
                int e = e0 + rf * 16 + l15;
                if (e >= n_edges) e = n_edges - 1;
                const float* p = ef + (size_t)e * H + ks * 32 + lg * 8;
                float4 v0 = *(const float4*)p;
                float4 v1 = *(const float4*)(p + 4);
                f16x8 h;
                h[0] = (f16)v0.x; h[1] = (f16)v0.y; h[2] = (f16)v0.z; h[3] = (f16)v0.w;
                h[4] = (f16)v1.x; h[5] = (f16)v1.y; h[6] = (f16)v1.z; h[7] = (f16)v1.w;
                a[rf] = h;
            }
#pragma unroll
            for (int cf = 0; cf < 8; ++cf) {
                const int c = cf * 16 + l15;
                unsigned off = ((unsigned)(2 * 32768 + c * 256 + (ks * 32 + lg * 8) * 2))
                               ^ ((unsigned)((c & 7) << 4));
                f16x8 bf = *(const f16x8*)((const char*)Wlds + off);
#pragma unroll
                for (int rf = 0; rf < 4; ++rf)
                    acc[rf][cf] = __builtin_amdgcn_mfma_f32_16x16x32_f16(
                        a[rf], bf, acc[rf][cf], 0, 0, 0);
            }
        }
#pragma unroll
        for (int rf = 0; rf < 4; ++rf) {
#pragma unroll
            for (int q = 0; q < 4; ++q) {
                const int e = e0 + rf * 16 + lg * 4 + q;
                if (e < n_edges) {
                    const int r = receivers[e];
                    float* dst = out + (size_t)r * H;
#pragma unroll
                    for (int cf = 0; cf < 8; ++cf) {
                        float m = fmaxf(acc[rf][cf][q] + bias[cf], 0.f);
                        atomicAdd(dst + cf * 16 + l15, m);
                    }
                }
            }
        }
    }
}

__global__ __launch_bounds__(256, 4)
void ln_kernel(const float* __restrict__ nf, const float* __restrict__ lnw,
               const float* __restrict__ lnb, float* __restrict__ out, int n_nodes) {
    const int wv = threadIdx.x >> 6;
    const int lane = threadIdx.x & 63;
    const int row = blockIdx.x * (blockDim.x >> 6) + wv;
    if (row >= n_nodes) return;
    float2 a = ((const float2*)(nf + (size_t)row * H))[lane];
    float2 g = ((float2*)(out + (size_t)row * H))[lane];
    float vx = a.x + g.x, vy = a.y + g.y;
    float s = vx + vy;
#pragma unroll
    for (int m = 32; m; m >>= 1) s += __shfl_xor(s, m, 64);
    float mu = s * (1.f / H);
    float dx = vx - mu, dy = vy - mu;
    float q = dx * dx + dy * dy;
#pragma unroll
    for (int m = 32; m; m >>= 1) q += __shfl_xor(q, m, 64);
    float rs = rsqrtf(q * (1.f / H) + 1e-5f);
    float2 w2 = ((const float2*)lnw)[lane];
    float2 b2 = ((const float2*)lnb)[lane];
    float2 o;
    o.x = dx * rs * w2.x + b2.x;
    o.y = dy * rs * w2.y + b2.y;
    ((float2*)(out + (size_t)row * H))[lane] = o;
}

__global__ void naive_edge_kernel(const float* __restrict__ nf, const int* __restrict__ s,
                                  const int* __restrict__ r, const float* __restrict__ ef,
                                  const float* __restrict__ W, const float* __restrict__ b,
                                  float* __restrict__ out, int n_edges) {
    int e = blockIdx.x * 2 + (threadIdx.x >> 7);
    int c = threadIdx.x & 127;
    if (e >= n_edges) return;
    int se = s[e], re = r[e];
    float acc = b[c];
    for (int k = 0; k < H; ++k) {
        acc += nf[(size_t)se * H + k] * W[(size_t)k * H + c];
        acc += nf[(size_t)re * H + k] * W[(size_t)(H + k) * H + c];
        acc += ef[(size_t)e * H + k] * W[(size_t)(2 * H + k) * H + c];
    }
    atomicAdd(&out[(size_t)re * H + c], fmaxf(acc, 0.f));
}

// ---------------------------------------------------------------------------
extern "C" void kernel_launch(void* const* d_in, const int* in_sizes, int n_in,
                              void* d_out, int out_size, void* d_ws, size_t ws_size,
                              hipStream_t stream) {
    const float* nf        = (const float*)d_in[0];
    const int*   senders   = (const int*)d_in[1];
    const int*   receivers = (const int*)d_in[2];
    const float* ef        = (const float*)d_in[3];
    const float* W         = (const float*)d_in[4];
    const float* b         = (const float*)d_in[5];
    const float* lnw       = (const float*)d_in[6];
    const float* lnb       = (const float*)d_in[7];
    float* out = (float*)d_out;

    const int n_nodes = in_sizes[0] / H;  // 50000
    const int n_edges = in_sizes[1];      // 800000
    const int nfelem = n_nodes * H;

    // ws carve-out (256B aligned)
    size_t o = 0;
    auto carve = [&](size_t bytes) { size_t r = o; o += (bytes + 255) & ~(size_t)255; return r; };
    const size_t o_wbuf   = carve((size_t)NSRC * H * H * sizeof(f16));   // 96 KB
    const size_t o_nfh    = carve((size_t)nfelem * sizeof(f16));         // 12.8 MB
    const size_t o_cnt    = carve((size_t)n_nodes * 4);
    const size_t o_rowptr = carve((size_t)(n_nodes + 1) * 4);
    const size_t o_cursor = carve((size_t)n_nodes * 4);
    const size_t o_perm   = carve((size_t)n_edges * 4);
    const size_t o_ssend  = carve((size_t)n_edges * 4);
    const size_t o_srecv  = carve((size_t)n_edges * 4);
    const size_t o_agg    = carve((size_t)nfelem * sizeof(float));       // 25.6 MB
    const size_t need_full = o;

    char* ws = (char*)d_ws;
    f16* wbuf = (f16*)(ws + o_wbuf);
    f16* nfh  = (f16*)(ws + o_nfh);

    if (ws_size >= need_full) {
        int* cnt    = (int*)(ws + o_cnt);
        int* rowptr = (int*)(ws + o_rowptr);
        int* cursor = (int*)(ws + o_cursor);
        int* perm   = (int*)(ws + o_perm);
        int* ssend  = (int*)(ws + o_ssend);
        int* srecv  = (int*)(ws + o_srecv);
        float* AGG  = (float*)(ws + o_agg);

        setup_kernel<<<2048, 256, 0, stream>>>(W, wbuf, cnt, (float4*)AGG,
                                               n_nodes, nfelem / 4, nf, nfh, nfelem / 4);
        hist_kernel<<<(n_edges + 255) / 256, 256, 0, stream>>>(receivers, cnt, n_edges);
        scan_kernel<<<1, 1024, 0, stream>>>(cnt, rowptr, cursor, n_nodes);
        scatter_kernel<<<(n_edges + 255) / 256, 256, 0, stream>>>(
            senders, receivers, cursor, perm, ssend, srecv, n_edges);

        fused_msg_kernel<<<1024, 256, 0, stream>>>(nfh, ef, perm, ssend, srecv,
                                                   wbuf, b, AGG, n_edges);
        ln_agg_kernel<<<(n_nodes + 3) / 4, 256, 0, stream>>>(nf, AGG, lnw, lnb, out, n_nodes);
    } else if (ws_size >= o_cnt) {  // enough for wbuf + nfh: R4 fallback
        hipMemsetAsync(d_out, 0, (size_t)nfelem * sizeof(float), stream);
        setup_kernel<<<2048, 256, 0, stream>>>(W, wbuf, (int*)(ws + o_wbuf), nullptr,
                                               0, 0, nf, nfh, nfelem / 4);
        fused_edge_kernel<<<512, 512, 0, stream>>>(nfh, senders, receivers, ef, b,
                                                   wbuf, out, n_edges);
        ln_kernel<<<(n_nodes + 3) / 4, 256, 0, stream>>>(nf, lnw, lnb, out, n_nodes);
    } else {
        hipMemsetAsync(d_out, 0, (size_t)nfelem * sizeof(float), stream);
        naive_edge_kernel<<<(n_edges + 1) / 2, 256, 0, stream>>>(
            nf, senders, receivers, ef, W, b, out, n_edges);
        ln_kernel<<<(n_nodes + 3) / 4, 256, 0, stream>>>(nf, lnw, lnb, out, n_nodes);
    }
}